// Round 20
// baseline (53.487 us; speedup 1.0000x reference)
//
#include <hip/hip_runtime.h>
#include <hip/hip_bf16.h>

#define BATCH 8
#define SEQ   2048
#define CDIM  1024
#define HDIM  64
#define NROWS (BATCH*SEQ)   // 16384
#define NSPLIT 8

typedef __attribute__((ext_vector_type(8))) short bf16x8;
typedef __attribute__((ext_vector_type(4))) float f32x4;

// 0.125 (1/sqrt(64)) * log2(e) — folded into Wq so QK^T emerges in exp2 units
#define QSCALE 0.18033688011112042f
// fixed softmax shift (exp2 units): scores bounded ~±8 << 24.  softmax is
// shift-invariant -> partials ADDITIVE (validated R6-R19: absmax 0.0156) ->
// cross-block merge = plain sums over per-split buffers.
#define SFIX 24.0f

__device__ inline ushort f2bf(float f) {
    union { float f; uint u; } x; x.f = f;
    uint r = (x.u + 0x7fffu + ((x.u >> 16) & 1u)) >> 16;
    return (ushort)r;
}

// lgkm-only barrier (NO sched_barrier — R16's version pinned the scheduler,
// m141's lesson, confounding the test).  Drains ds ops (the only cross-wave
// state) but lets register-private global loads ride across the barrier; the
// __syncthreads vmcnt(0) drain was capping in-flight HBM bytes at ~1 step.
#define BARRIER_LGKM()                                                        \
    do {                                                                      \
        asm volatile("s_waitcnt lgkmcnt(0)" ::: "memory");                    \
        __builtin_amdgcn_s_barrier();                                         \
    } while (0)

// ---------------------------------------------------------------------------
// Kernel 0: pack W^T into bf16  wp[192][1024].  Coalesced: stage W[c][n]
// fp32 rows into LDS (transposed, padded stride 132), write wp[n][c] rows
// coalesced.  24 blocks = 3 matrices x 8 c-blocks.
// ---------------------------------------------------------------------------
__global__ __launch_bounds__(256) void wpack_kernel(
    const float* __restrict__ Wq, const float* __restrict__ Wk,
    const float* __restrict__ Wv, ushort* __restrict__ wp)
{
    __shared__ ushort lt[64][132];
    const int which = blockIdx.x >> 3;         // 0..2
    const int cblk  = blockIdx.x & 7;          // 0..7
    const float* W = (which == 0) ? Wq : (which == 1) ? Wk : Wv;
    const float sc = (which == 0) ? QSCALE : 1.0f;
    const int t = threadIdx.x;
    const float4* Wb = reinterpret_cast<const float4*>(W + (size_t)cblk * 128 * 64);
    #pragma unroll
    for (int j = 0; j < 8; ++j) {
        const int off4 = j * 256 + t;          // 0..2047
        float4 v = Wb[off4];
        const int c = off4 >> 4;               // 0..127
        const int n0 = (off4 & 15) * 4;        // 0..60
        lt[n0 + 0][c] = f2bf(v.x * sc);
        lt[n0 + 1][c] = f2bf(v.y * sc);
        lt[n0 + 2][c] = f2bf(v.z * sc);
        lt[n0 + 3][c] = f2bf(v.w * sc);
    }
    __syncthreads();
    const int n = t >> 2, cq = (t & 3) * 32;
    ushort* dst = wp + (size_t)(which * 64 + n) * CDIM + cblk * 128 + cq;
    #pragma unroll
    for (int k = 0; k < 32; ++k) dst[k] = lt[n][cq + k];
}

// ---------------------------------------------------------------------------
// Kernel 1: QKV GEMM — R13 structure, K-loop barriers lgkm-only (clean
// re-test of the vmcnt-drain theory without R16's sched_barrier confound).
// BM=32 -> 512 blocks (2/CU); 512 thr = 8 waves = 2 rowg x 4 colg.
// ---------------------------------------------------------------------------
__global__ __launch_bounds__(512, 4) void qkv_gemm(
    const float* __restrict__ x, const ushort* __restrict__ wp,
    ushort* __restrict__ qb, ushort* __restrict__ kbuf, ushort* __restrict__ vt)
{
    __shared__ ushort xs[2][32 * 64];    // 8KB   [row][c] bf16, XOR-swizzled
    __shared__ ushort ws[2][192 * 64];   // 48KB  [n][c]  bf16, XOR-swizzled
    const int t = threadIdx.x;
    const int w = t >> 6, lane = t & 63;
    const int l15 = lane & 15, hi = lane >> 4;
    const int rowg = w & 1, colg = w >> 1;
    const int m0 = blockIdx.x * 32;

    f32x4 acc[3];
    #pragma unroll
    for (int i = 0; i < 3; ++i) acc[i] = (f32x4){0.f, 0.f, 0.f, 0.f};

    const int xrow = t >> 4, xc4 = t & 15;
    const int wn0 = t >> 3,          wc0 = t & 7;
    const int wn1 = (t + 512) >> 3,  wc1 = (t + 512) & 7;
    const int wn2 = (t + 1024) >> 3, wc2 = (t + 1024) & 7;

    float4 xra, xrb;
    uint4 wra0, wra1, wra2, wrb0, wrb1, wrb2;

#define LOADS(S, KK)                                                           \
    xr##S = reinterpret_cast<const float4*>(x + (size_t)(m0 + xrow) * CDIM + (KK))[xc4]; \
    wr##S##0 = reinterpret_cast<const uint4*>(wp + (size_t)wn0 * CDIM + (KK))[wc0]; \
    wr##S##1 = reinterpret_cast<const uint4*>(wp + (size_t)wn1 * CDIM + (KK))[wc1]; \
    wr##S##2 = reinterpret_cast<const uint4*>(wp + (size_t)wn2 * CDIM + (KK))[wc2];

#define WRITES(S, BUF)                                                         \
    {                                                                          \
        ushort4 bx = make_ushort4(f2bf(xr##S.x), f2bf(xr##S.y), f2bf(xr##S.z), f2bf(xr##S.w)); \
        int xb = (xrow * 128 + xc4 * 8) ^ ((xrow & 7) << 4);                   \
        *reinterpret_cast<ushort4*>(reinterpret_cast<char*>(xs[BUF]) + xb) = bx; \
        int y0 = (wn0 * 128 + wc0 * 16) ^ ((wn0 & 7) << 4);                    \
        int y1 = (wn1 * 128 + wc1 * 16) ^ ((wn1 & 7) << 4);                    \
        int y2 = (wn2 * 128 + wc2 * 16) ^ ((wn2 & 7) << 4);                    \
        *reinterpret_cast<uint4*>(reinterpret_cast<char*>(ws[BUF]) + y0) = wr##S##0; \
        *reinterpret_cast<uint4*>(reinterpret_cast<char*>(ws[BUF]) + y1) = wr##S##1; \
        *reinterpret_cast<uint4*>(reinterpret_cast<char*>(ws[BUF]) + y2) = wr##S##2; \
    }

#define MFMA_STEP(BUF)                                                         \
    {                                                                          \
        const int arow = rowg * 16 + l15;                                      \
        _Pragma("unroll")                                                      \
        for (int c32 = 0; c32 < 2; ++c32) {                                    \
            const int abyte = (arow * 128 + hi * 16 + c32 * 64) ^ ((arow & 7) << 4); \
            bf16x8 a = *reinterpret_cast<const bf16x8*>(reinterpret_cast<char*>(xs[BUF]) + abyte); \
            _Pragma("unroll")                                                  \
            for (int nf = 0; nf < 3; ++nf) {                                   \
                const int n = colg * 48 + nf * 16 + l15;                       \
                const int bbyte = (n * 128 + hi * 16 + c32 * 64) ^ ((n & 7) << 4); \
                bf16x8 b = *reinterpret_cast<const bf16x8*>(reinterpret_cast<char*>(ws[BUF]) + bbyte); \
                acc[nf] = __builtin_amdgcn_mfma_f32_16x16x32_bf16(a, b, acc[nf], 0, 0, 0); \
            }                                                                  \
        }                                                                      \
    }

    LOADS(a, 0)
    LOADS(b, 64)
    WRITES(a, 0)
    BARRIER_LGKM();                      // LOADS(b) stays in flight

    for (int step = 0; step < 16; step += 2) {
        if (step + 2 < 16) { LOADS(a, (step + 2) * 64) }
        MFMA_STEP(0)
        WRITES(b, 1)
        BARRIER_LGKM();                  // LOADS(a,step+2) stays in flight
        if (step + 3 < 16) { LOADS(b, (step + 3) * 64) }
        MFMA_STEP(1)
        if (step + 2 < 16) { WRITES(a, 0) }
        BARRIER_LGKM();                  // LOADS(b,step+3) stays in flight
    }
#undef LOADS
#undef WRITES
#undef MFMA_STEP

    #pragma unroll
    for (int nf = 0; nf < 3; ++nf) {
        const int n = colg * 48 + nf * 16 + l15;
        #pragma unroll
        for (int r = 0; r < 4; ++r) {
            const int grow = m0 + rowg * 16 + hi * 4 + r;
            const ushort bv = f2bf(acc[nf][r]);
            if (n < 64) {
                qb[(size_t)grow * 64 + n] = bv;
            } else if (n < 128) {
                kbuf[(size_t)grow * 64 + (n - 64)] = bv;
            } else {
                const int b = grow >> 11, tt = grow & 2047;
                vt[(((size_t)b * 64 + (n - 128)) << 11) + tt] = bv;
            }
        }
    }
}

// ---------------------------------------------------------------------------
// Kernel 2: flash attention, LDS-shared K/V (R13 exact; 16.6us measured).
// ---------------------------------------------------------------------------
__global__ __launch_bounds__(256, 4) void attn_flash(
    const ushort* __restrict__ qb, const ushort* __restrict__ kbuf,
    const ushort* __restrict__ vt, ushort* __restrict__ Opart,
    float* __restrict__ lpart)
{
    __shared__ ushort kst[2][64 * 64];   // 16KB  K tile, XOR-swizzled
    __shared__ ushort vst[2][64 * 64];   // 16KB  V tile (vt layout [d][t])
    __shared__ ushort P[4][1024];        // 8KB   per-wave P round-trip

    const int t = threadIdx.x;
    const int w = t >> 6, lane = t & 63;
    const int l15 = lane & 15, hi = lane >> 4;
    const int bid = blockIdx.x;
    const int pid = (bid & 7) * 128 + (bid >> 3);   // XCD x -> batch x
    const int batch = pid >> 7;
    const int rem = pid & 127;
    const int pairIdx = rem >> 3;        // 0..15
    const int s = rem & 7;               // split 0..7
    const int qtA = pairIdx, qtB = 31 - pairIdx;    // 64-row q-tiles
    const int ntA = qtA + 1;             // ntA + ntB == 33

    const ushort* kB = kbuf + (size_t)batch * SEQ * 64;
    const ushort* vB = vt + (size_t)batch * 64 * SEQ;
    ushort* Osp = Opart + (size_t)s * NROWS * 64;
    float* lsp = lpart + (size_t)s * NROWS;
    char* pw = reinterpret_cast<char*>(P[w]);

    const int r0 = t >> 3, c8 = t & 7;   // chunk0 row 0..31
    const int r1 = r0 + 32;              // chunk1 row 32..63
    const int sb0 = (r0 * 128 + c8 * 16) ^ ((r0 & 7) << 4);
    const int sb1 = (r1 * 128 + c8 * 16) ^ ((r1 & 7) << 4);

    uint4 kr0, kr1, vr0, vr1;

#define STAGE_ISSUE(C)                                                        \
    {                                                                         \
        const int kt_ = ((C) >= ntA) ? ((C) - ntA) : (C);                     \
        const int j0_ = kt_ * 64;                                             \
        kr0 = *reinterpret_cast<const uint4*>(kB + (size_t)(j0_ + r0) * 64 + c8 * 8); \
        kr1 = *reinterpret_cast<const uint4*>(kB + (size_t)(j0_ + r1) * 64 + c8 * 8); \
        vr0 = *reinterpret_cast<const uint4*>(vB + (size_t)r0 * SEQ + j0_ + c8 * 8);  \
        vr1 = *reinterpret_cast<const uint4*>(vB + (size_t)r1 * SEQ + j0_ + c8 * 8);  \
    }

#define STAGE_WRITE(BUF)                                                      \
    {                                                                         \
        *reinterpret_cast<uint4*>(reinterpret_cast<char*>(kst[BUF]) + sb0) = kr0; \
        *reinterpret_cast<uint4*>(reinterpret_cast<char*>(kst[BUF]) + sb1) = kr1; \
        *reinterpret_cast<uint4*>(reinterpret_cast<char*>(vst[BUF]) + sb0) = vr0; \
        *reinterpret_cast<uint4*>(reinterpret_cast<char*>(vst[BUF]) + sb1) = vr1; \
    }

#define LOADQ(QT)                                                             \
    {                                                                         \
        const ushort* qp_ = qb + (size_t)(batch * SEQ + (QT) * 64 + w * 16 + l15) * 64 + hi * 8; \
        aq0 = *reinterpret_cast<const bf16x8*>(qp_);                          \
        aq1 = *reinterpret_cast<const bf16x8*>(qp_ + 32);                     \
    }

#define DUMP(QT)                                                              \
    {                                                                         \
        _Pragma("unroll")                                                     \
        for (int dt = 0; dt < 4; ++dt)                                        \
            _Pragma("unroll")                                                 \
            for (int r = 0; r < 4; ++r)                                       \
                Osp[(size_t)(batch * SEQ + (QT) * 64 + w * 16 + hi * 4 + r) * 64 + dt * 16 + l15] = f2bf(O[dt][r]); \
        _Pragma("unroll")                                                     \
        for (int r = 0; r < 4; ++r) {                                         \
            float s_ = lsum[r];                                               \
            s_ += __shfl_xor(s_, 1, 64);                                      \
            s_ += __shfl_xor(s_, 2, 64);                                      \
            s_ += __shfl_xor(s_, 4, 64);                                      \
            s_ += __shfl_xor(s_, 8, 64);                                      \
            if (l15 == 0)                                                     \
                lsp[batch * SEQ + (QT) * 64 + w * 16 + hi * 4 + r] = s_;      \
        }                                                                     \
    }

#define RESET_STATE()                                                         \
    {                                                                         \
        _Pragma("unroll")                                                     \
        for (int i = 0; i < 4; ++i) {                                         \
            O[i] = (f32x4){0.f, 0.f, 0.f, 0.f};                               \
            lsum[i] = 0.f;                                                    \
        }                                                                     \
    }

    bf16x8 aq0, aq1;
    LOADQ(qtA)
    f32x4 O[4];
    float lsum[4];
    RESET_STATE()

    STAGE_ISSUE(s)
    STAGE_WRITE(0)
    __syncthreads();

    int curB = 0, cur = 0;
    for (int c = s; c < 33; c += 8) {
        if (c + 8 < 33) { STAGE_ISSUE(c + 8) }    // in flight over compute
        if (c >= ntA && !curB) {                  // block-uniform A -> B
            DUMP(qtA)
            RESET_STATE()
            LOADQ(qtB)
            curB = 1;
        }
        const int qt = curB ? qtB : qtA;
        const int kt = curB ? (c - ntA) : c;
        const int j0 = kt * 64;
        const int qrow0 = qt * 64 + w * 16;
        const bool diag = curB ? (c == 32) : (c == ntA - 1);

        const char* kc = reinterpret_cast<const char*>(kst[cur]);
        const char* vc = reinterpret_cast<const char*>(vst[cur]);

        // ---- QK^T from LDS K ----
        f32x4 S[4];
        #pragma unroll
        for (int kb = 0; kb < 4; ++kb) {
            const int key = kb * 16 + l15;
            const int sw = (key & 7) << 4;
            bf16x8 b0 = *reinterpret_cast<const bf16x8*>(kc + ((key * 128 + hi * 16) ^ sw));
            bf16x8 b1 = *reinterpret_cast<const bf16x8*>(kc + ((key * 128 + hi * 16 + 64) ^ sw));
            f32x4 z = (f32x4){0.f, 0.f, 0.f, 0.f};
            z = __builtin_amdgcn_mfma_f32_16x16x32_bf16(aq0, b0, z, 0, 0, 0);
            z = __builtin_amdgcn_mfma_f32_16x16x32_bf16(aq1, b1, z, 0, 0, 0);
            S[kb] = z;
        }
        // ---- causal mask: only the diagonal tile ----
        if (diag) {
            #pragma unroll
            for (int kb = 0; kb < 4; ++kb) {
                const int key = j0 + kb * 16 + l15;
                #pragma unroll
                for (int r = 0; r < 4; ++r) {
                    const int qr = qrow0 + hi * 4 + r;
                    if (key > qr) S[kb][r] = -1e30f;
                }
            }
        }
        // ---- fixed-shift softmax ----
        #pragma unroll
        for (int kb = 0; kb < 4; ++kb)
            #pragma unroll
            for (int r = 0; r < 4; ++r)
                S[kb][r] = exp2f(S[kb][r] - SFIX);
        #pragma unroll
        for (int r = 0; r < 4; ++r)
            lsum[r] += (S[0][r] + S[1][r]) + (S[2][r] + S[3][r]);

        // ---- P: C-layout -> per-wave LDS (swizzled) -> A-layout ----
        #pragma unroll
        for (int kb = 0; kb < 4; ++kb) {
            #pragma unroll
            for (int r = 0; r < 4; ++r) {
                const int prow = hi * 4 + r;
                const int pcol = kb * 16 + l15;
                const int byte = (prow * 128 + pcol * 2) ^ ((prow & 7) << 4);
                *reinterpret_cast<ushort*>(pw + byte) = f2bf(S[kb][r]);
            }
        }
        asm volatile("" ::: "memory");   // intra-wave LDS in-order
        const int pb0 = (l15 * 128 + hi * 16) ^ ((l15 & 7) << 4);
        const int pb1 = (l15 * 128 + hi * 16 + 64) ^ ((l15 & 7) << 4);
        bf16x8 pa0 = *reinterpret_cast<const bf16x8*>(pw + pb0);
        bf16x8 pa1 = *reinterpret_cast<const bf16x8*>(pw + pb1);
        // ---- PV from LDS V ----
        #pragma unroll
        for (int dt = 0; dt < 4; ++dt) {
            const int d = dt * 16 + l15;
            const int sw = (d & 7) << 4;
            bf16x8 v0 = *reinterpret_cast<const bf16x8*>(vc + ((d * 128 + hi * 16) ^ sw));
            bf16x8 v1 = *reinterpret_cast<const bf16x8*>(vc + ((d * 128 + hi * 16 + 64) ^ sw));
            O[dt] = __builtin_amdgcn_mfma_f32_16x16x32_bf16(pa0, v0, O[dt], 0, 0, 0);
            O[dt] = __builtin_amdgcn_mfma_f32_16x16x32_bf16(pa1, v1, O[dt], 0, 0, 0);
        }
        if (c + 8 < 33) { STAGE_WRITE(cur ^ 1) }
        __syncthreads();
        cur ^= 1;
    }

    DUMP(qtB)    // curB==1 always on exit
#undef STAGE_ISSUE
#undef STAGE_WRITE
#undef LOADQ
#undef DUMP
#undef RESET_STATE
}

// ---------------------------------------------------------------------------
// Kernel 3: out = Σ_s Opart[s] / Σ_s lpart[s].  bf16 partial reads, fp32
// accumulate, float4 x2 stores.  131072 threads.
// ---------------------------------------------------------------------------
__global__ __launch_bounds__(256) void merge_kernel(
    const ushort* __restrict__ Opart, const float* __restrict__ lpart,
    float* __restrict__ out)
{
    const int idx = blockIdx.x * 256 + threadIdx.x;    // 0..131071
    const int row = idx >> 3;
    float acc[8] = {0.f, 0.f, 0.f, 0.f, 0.f, 0.f, 0.f, 0.f};
    float lv = 0.f;
    #pragma unroll
    for (int s = 0; s < NSPLIT; ++s) {
        uint4 v = reinterpret_cast<const uint4*>(Opart + (size_t)s * NROWS * 64)[idx];
        const uint u0 = v.x, u1 = v.y, u2 = v.z, u3 = v.w;
        acc[0] += __uint_as_float((u0 & 0xffffu) << 16);
        acc[1] += __uint_as_float(u0 & 0xffff0000u);
        acc[2] += __uint_as_float((u1 & 0xffffu) << 16);
        acc[3] += __uint_as_float(u1 & 0xffff0000u);
        acc[4] += __uint_as_float((u2 & 0xffffu) << 16);
        acc[5] += __uint_as_float(u2 & 0xffff0000u);
        acc[6] += __uint_as_float((u3 & 0xffffu) << 16);
        acc[7] += __uint_as_float(u3 & 0xffff0000u);
        lv += lpart[s * NROWS + row];
    }
    const float inv = 1.0f / lv;
    float4 o0 = make_float4(acc[0] * inv, acc[1] * inv, acc[2] * inv, acc[3] * inv);
    float4 o1 = make_float4(acc[4] * inv, acc[5] * inv, acc[6] * inv, acc[7] * inv);
    reinterpret_cast<float4*>(out)[idx * 2]     = o0;
    reinterpret_cast<float4*>(out)[idx * 2 + 1] = o1;
}

extern "C" void kernel_launch(void* const* d_in, const int* in_sizes, int n_in,
                              void* d_out, int out_size, void* d_ws, size_t ws_size,
                              hipStream_t stream) {
    const float* x  = (const float*)d_in[0];
    const float* Wq = (const float*)d_in[1];
    const float* Wk = (const float*)d_in[2];
    const float* Wv = (const float*)d_in[3];
    float* out = (float*)d_out;

    ushort* qb   = (ushort*)d_ws;                    // 2MB
    ushort* kbuf = qb + (size_t)NROWS * 64;          // 2MB
    ushort* vt   = kbuf + (size_t)NROWS * 64;        // 2MB (transposed V)
    ushort* wp   = vt + (size_t)NROWS * 64;          // 384KB packed W^T
    float* lpart = (float*)(wp + 192 * 1024);        // 512KB  8 x row-sums
    ushort* Opart = (ushort*)(lpart + (size_t)NSPLIT * NROWS);  // 16MB  8 x bf16 O partials

    wpack_kernel<<<24, 256, 0, stream>>>(Wq, Wk, Wv, wp);
    qkv_gemm<<<NROWS / 32, 512, 0, stream>>>(x, wp, qb, kbuf, vt);
    attn_flash<<<1024, 256, 0, stream>>>(qb, kbuf, vt, Opart, lpart);
    merge_kernel<<<(NROWS * HDIM / 8) / 256, 256, 0, stream>>>(Opart, lpart, out);
}

// Round 21
// 50.679 us; speedup vs baseline: 1.0554x; 1.0554x over previous
//
#include <hip/hip_runtime.h>
#include <hip/hip_bf16.h>

#define BATCH 8
#define SEQ   2048
#define CDIM  1024
#define HDIM  64
#define NROWS (BATCH*SEQ)   // 16384
#define NSPLIT 8

typedef __attribute__((ext_vector_type(8))) short bf16x8;
typedef __attribute__((ext_vector_type(4))) float f32x4;

// 0.125 (1/sqrt(64)) * log2(e) — folded into Wq so QK^T emerges in exp2 units
#define QSCALE 0.18033688011112042f
// fixed softmax shift (exp2 units): scores bounded ~±8 << 24.  softmax is
// shift-invariant -> partials ADDITIVE (validated R6-R20: absmax 0.0156) ->
// cross-block merge = plain sums over per-split buffers.
#define SFIX 24.0f

__device__ inline ushort f2bf(float f) {
    union { float f; uint u; } x; x.f = f;
    uint r = (x.u + 0x7fffu + ((x.u >> 16) & 1u)) >> 16;
    return (ushort)r;
}

// ---------------------------------------------------------------------------
// Kernel 0: pack W^T into bf16  wp[192][1024] (R13 exact).
// ---------------------------------------------------------------------------
__global__ __launch_bounds__(256) void wpack_kernel(
    const float* __restrict__ Wq, const float* __restrict__ Wk,
    const float* __restrict__ Wv, ushort* __restrict__ wp)
{
    __shared__ ushort lt[64][132];
    const int which = blockIdx.x >> 3;         // 0..2
    const int cblk  = blockIdx.x & 7;          // 0..7
    const float* W = (which == 0) ? Wq : (which == 1) ? Wk : Wv;
    const float sc = (which == 0) ? QSCALE : 1.0f;
    const int t = threadIdx.x;
    const float4* Wb = reinterpret_cast<const float4*>(W + (size_t)cblk * 128 * 64);
    #pragma unroll
    for (int j = 0; j < 8; ++j) {
        const int off4 = j * 256 + t;          // 0..2047
        float4 v = Wb[off4];
        const int c = off4 >> 4;               // 0..127
        const int n0 = (off4 & 15) * 4;        // 0..60
        lt[n0 + 0][c] = f2bf(v.x * sc);
        lt[n0 + 1][c] = f2bf(v.y * sc);
        lt[n0 + 2][c] = f2bf(v.z * sc);
        lt[n0 + 3][c] = f2bf(v.w * sc);
    }
    __syncthreads();
    const int n = t >> 2, cq = (t & 3) * 32;
    ushort* dst = wp + (size_t)(which * 64 + n) * CDIM + cblk * 128 + cq;
    #pragma unroll
    for (int k = 0; k < 32; ++k) dst[k] = lt[n][cq + k];
}

// ---------------------------------------------------------------------------
// Kernel 1: QKV GEMM — R13 structure/staging, ONE change: 768-thread blocks
// (12 waves = 2 rowg x 6 colg, wave = 16 rows x 32 cols, acc[2]).  Same
// BM=32 / 512 blocks / 56KB LDS -> still 2 blocks/CU, but 24 waves/CU (75%)
// instead of 16 (50%).  Occupancy is the one gemm dimension never varied
// across the four ~17.3us staging variants.
// ---------------------------------------------------------------------------
__global__ __launch_bounds__(768, 2) void qkv_gemm(
    const float* __restrict__ x, const ushort* __restrict__ wp,
    ushort* __restrict__ qb, ushort* __restrict__ kbuf, ushort* __restrict__ vt)
{
    __shared__ ushort xs[2][32 * 64];    // 8KB   [row][c] bf16, XOR-swizzled
    __shared__ ushort ws[2][192 * 64];   // 48KB  [n][c]  bf16, XOR-swizzled
    const int t = threadIdx.x;
    const int w = t >> 6, lane = t & 63;
    const int l15 = lane & 15, hi = lane >> 4;
    const int rowg = w & 1, colg = w >> 1;     // colg 0..5
    const int m0 = blockIdx.x * 32;

    f32x4 acc[2];
    #pragma unroll
    for (int i = 0; i < 2; ++i) acc[i] = (f32x4){0.f, 0.f, 0.f, 0.f};

    // x staging: 512 float4 chunks, threads 0..511 (wave-uniform guard)
    const int xrow = t >> 4, xc4 = t & 15;
    // W staging: 1536 uint4 chunks / 768 threads = 2 each
    const int wn0 = t >> 3,          wc0 = t & 7;
    const int wn1 = (t + 768) >> 3,  wc1 = (t + 768) & 7;

    float4 xra, xrb;
    uint4 wra0, wra1, wrb0, wrb1;

#define LOADS(S, KK)                                                           \
    if (t < 512)                                                               \
        xr##S = reinterpret_cast<const float4*>(x + (size_t)(m0 + xrow) * CDIM + (KK))[xc4]; \
    wr##S##0 = reinterpret_cast<const uint4*>(wp + (size_t)wn0 * CDIM + (KK))[wc0]; \
    wr##S##1 = reinterpret_cast<const uint4*>(wp + (size_t)wn1 * CDIM + (KK))[wc1];

#define WRITES(S, BUF)                                                         \
    {                                                                          \
        if (t < 512) {                                                         \
            ushort4 bx = make_ushort4(f2bf(xr##S.x), f2bf(xr##S.y), f2bf(xr##S.z), f2bf(xr##S.w)); \
            int xb = (xrow * 128 + xc4 * 8) ^ ((xrow & 7) << 4);               \
            *reinterpret_cast<ushort4*>(reinterpret_cast<char*>(xs[BUF]) + xb) = bx; \
        }                                                                      \
        int y0 = (wn0 * 128 + wc0 * 16) ^ ((wn0 & 7) << 4);                    \
        int y1 = (wn1 * 128 + wc1 * 16) ^ ((wn1 & 7) << 4);                    \
        *reinterpret_cast<uint4*>(reinterpret_cast<char*>(ws[BUF]) + y0) = wr##S##0; \
        *reinterpret_cast<uint4*>(reinterpret_cast<char*>(ws[BUF]) + y1) = wr##S##1; \
    }

#define MFMA_STEP(BUF)                                                         \
    {                                                                          \
        const int arow = rowg * 16 + l15;                                      \
        _Pragma("unroll")                                                      \
        for (int c32 = 0; c32 < 2; ++c32) {                                    \
            const int abyte = (arow * 128 + hi * 16 + c32 * 64) ^ ((arow & 7) << 4); \
            bf16x8 a = *reinterpret_cast<const bf16x8*>(reinterpret_cast<char*>(xs[BUF]) + abyte); \
            _Pragma("unroll")                                                  \
            for (int nf = 0; nf < 2; ++nf) {                                   \
                const int n = colg * 32 + nf * 16 + l15;                       \
                const int bbyte = (n * 128 + hi * 16 + c32 * 64) ^ ((n & 7) << 4); \
                bf16x8 b = *reinterpret_cast<const bf16x8*>(reinterpret_cast<char*>(ws[BUF]) + bbyte); \
                acc[nf] = __builtin_amdgcn_mfma_f32_16x16x32_bf16(a, b, acc[nf], 0, 0, 0); \
            }                                                                  \
        }                                                                      \
    }

    LOADS(a, 0)
    LOADS(b, 64)
    WRITES(a, 0)
    __syncthreads();

    for (int step = 0; step < 16; step += 2) {
        if (step + 2 < 16) { LOADS(a, (step + 2) * 64) }
        MFMA_STEP(0)
        WRITES(b, 1)
        __syncthreads();
        if (step + 3 < 16) { LOADS(b, (step + 3) * 64) }
        MFMA_STEP(1)
        if (step + 2 < 16) { WRITES(a, 0) }
        __syncthreads();
    }
#undef LOADS
#undef WRITES
#undef MFMA_STEP

    // epilogue: C layout col = l15 (n), row = hi*4 + r
    #pragma unroll
    for (int nf = 0; nf < 2; ++nf) {
        const int n = colg * 32 + nf * 16 + l15;
        #pragma unroll
        for (int r = 0; r < 4; ++r) {
            const int grow = m0 + rowg * 16 + hi * 4 + r;
            const ushort bv = f2bf(acc[nf][r]);
            if (n < 64) {
                qb[(size_t)grow * 64 + n] = bv;
            } else if (n < 128) {
                kbuf[(size_t)grow * 64 + (n - 64)] = bv;
            } else {
                const int b = grow >> 11, tt = grow & 2047;
                vt[(((size_t)b * 64 + (n - 128)) << 11) + tt] = bv;
            }
        }
    }
}

// ---------------------------------------------------------------------------
// Kernel 2: flash attention, LDS-shared K/V (R13 exact; 16.6us measured).
// ---------------------------------------------------------------------------
__global__ __launch_bounds__(256, 4) void attn_flash(
    const ushort* __restrict__ qb, const ushort* __restrict__ kbuf,
    const ushort* __restrict__ vt, ushort* __restrict__ Opart,
    float* __restrict__ lpart)
{
    __shared__ ushort kst[2][64 * 64];   // 16KB  K tile, XOR-swizzled
    __shared__ ushort vst[2][64 * 64];   // 16KB  V tile (vt layout [d][t])
    __shared__ ushort P[4][1024];        // 8KB   per-wave P round-trip

    const int t = threadIdx.x;
    const int w = t >> 6, lane = t & 63;
    const int l15 = lane & 15, hi = lane >> 4;
    const int bid = blockIdx.x;
    const int pid = (bid & 7) * 128 + (bid >> 3);   // XCD x -> batch x
    const int batch = pid >> 7;
    const int rem = pid & 127;
    const int pairIdx = rem >> 3;        // 0..15
    const int s = rem & 7;               // split 0..7
    const int qtA = pairIdx, qtB = 31 - pairIdx;    // 64-row q-tiles
    const int ntA = qtA + 1;             // ntA + ntB == 33

    const ushort* kB = kbuf + (size_t)batch * SEQ * 64;
    const ushort* vB = vt + (size_t)batch * 64 * SEQ;
    ushort* Osp = Opart + (size_t)s * NROWS * 64;
    float* lsp = lpart + (size_t)s * NROWS;
    char* pw = reinterpret_cast<char*>(P[w]);

    const int r0 = t >> 3, c8 = t & 7;   // chunk0 row 0..31
    const int r1 = r0 + 32;              // chunk1 row 32..63
    const int sb0 = (r0 * 128 + c8 * 16) ^ ((r0 & 7) << 4);
    const int sb1 = (r1 * 128 + c8 * 16) ^ ((r1 & 7) << 4);

    uint4 kr0, kr1, vr0, vr1;

#define STAGE_ISSUE(C)                                                        \
    {                                                                         \
        const int kt_ = ((C) >= ntA) ? ((C) - ntA) : (C);                     \
        const int j0_ = kt_ * 64;                                             \
        kr0 = *reinterpret_cast<const uint4*>(kB + (size_t)(j0_ + r0) * 64 + c8 * 8); \
        kr1 = *reinterpret_cast<const uint4*>(kB + (size_t)(j0_ + r1) * 64 + c8 * 8); \
        vr0 = *reinterpret_cast<const uint4*>(vB + (size_t)r0 * SEQ + j0_ + c8 * 8);  \
        vr1 = *reinterpret_cast<const uint4*>(vB + (size_t)r1 * SEQ + j0_ + c8 * 8);  \
    }

#define STAGE_WRITE(BUF)                                                      \
    {                                                                         \
        *reinterpret_cast<uint4*>(reinterpret_cast<char*>(kst[BUF]) + sb0) = kr0; \
        *reinterpret_cast<uint4*>(reinterpret_cast<char*>(kst[BUF]) + sb1) = kr1; \
        *reinterpret_cast<uint4*>(reinterpret_cast<char*>(vst[BUF]) + sb0) = vr0; \
        *reinterpret_cast<uint4*>(reinterpret_cast<char*>(vst[BUF]) + sb1) = vr1; \
    }

#define LOADQ(QT)                                                             \
    {                                                                         \
        const ushort* qp_ = qb + (size_t)(batch * SEQ + (QT) * 64 + w * 16 + l15) * 64 + hi * 8; \
        aq0 = *reinterpret_cast<const bf16x8*>(qp_);                          \
        aq1 = *reinterpret_cast<const bf16x8*>(qp_ + 32);                     \
    }

#define DUMP(QT)                                                              \
    {                                                                         \
        _Pragma("unroll")                                                     \
        for (int dt = 0; dt < 4; ++dt)                                        \
            _Pragma("unroll")                                                 \
            for (int r = 0; r < 4; ++r)                                       \
                Osp[(size_t)(batch * SEQ + (QT) * 64 + w * 16 + hi * 4 + r) * 64 + dt * 16 + l15] = f2bf(O[dt][r]); \
        _Pragma("unroll")                                                     \
        for (int r = 0; r < 4; ++r) {                                         \
            float s_ = lsum[r];                                               \
            s_ += __shfl_xor(s_, 1, 64);                                      \
            s_ += __shfl_xor(s_, 2, 64);                                      \
            s_ += __shfl_xor(s_, 4, 64);                                      \
            s_ += __shfl_xor(s_, 8, 64);                                      \
            if (l15 == 0)                                                     \
                lsp[batch * SEQ + (QT) * 64 + w * 16 + hi * 4 + r] = s_;      \
        }                                                                     \
    }

#define RESET_STATE()                                                         \
    {                                                                         \
        _Pragma("unroll")                                                     \
        for (int i = 0; i < 4; ++i) {                                         \
            O[i] = (f32x4){0.f, 0.f, 0.f, 0.f};                               \
            lsum[i] = 0.f;                                                    \
        }                                                                     \
    }

    bf16x8 aq0, aq1;
    LOADQ(qtA)
    f32x4 O[4];
    float lsum[4];
    RESET_STATE()

    STAGE_ISSUE(s)
    STAGE_WRITE(0)
    __syncthreads();

    int curB = 0, cur = 0;
    for (int c = s; c < 33; c += 8) {
        if (c + 8 < 33) { STAGE_ISSUE(c + 8) }    // in flight over compute
        if (c >= ntA && !curB) {                  // block-uniform A -> B
            DUMP(qtA)
            RESET_STATE()
            LOADQ(qtB)
            curB = 1;
        }
        const int qt = curB ? qtB : qtA;
        const int kt = curB ? (c - ntA) : c;
        const int j0 = kt * 64;
        const int qrow0 = qt * 64 + w * 16;
        const bool diag = curB ? (c == 32) : (c == ntA - 1);

        const char* kc = reinterpret_cast<const char*>(kst[cur]);
        const char* vc = reinterpret_cast<const char*>(vst[cur]);

        // ---- QK^T from LDS K ----
        f32x4 S[4];
        #pragma unroll
        for (int kb = 0; kb < 4; ++kb) {
            const int key = kb * 16 + l15;
            const int sw = (key & 7) << 4;
            bf16x8 b0 = *reinterpret_cast<const bf16x8*>(kc + ((key * 128 + hi * 16) ^ sw));
            bf16x8 b1 = *reinterpret_cast<const bf16x8*>(kc + ((key * 128 + hi * 16 + 64) ^ sw));
            f32x4 z = (f32x4){0.f, 0.f, 0.f, 0.f};
            z = __builtin_amdgcn_mfma_f32_16x16x32_bf16(aq0, b0, z, 0, 0, 0);
            z = __builtin_amdgcn_mfma_f32_16x16x32_bf16(aq1, b1, z, 0, 0, 0);
            S[kb] = z;
        }
        // ---- causal mask: only the diagonal tile ----
        if (diag) {
            #pragma unroll
            for (int kb = 0; kb < 4; ++kb) {
                const int key = j0 + kb * 16 + l15;
                #pragma unroll
                for (int r = 0; r < 4; ++r) {
                    const int qr = qrow0 + hi * 4 + r;
                    if (key > qr) S[kb][r] = -1e30f;
                }
            }
        }
        // ---- fixed-shift softmax ----
        #pragma unroll
        for (int kb = 0; kb < 4; ++kb)
            #pragma unroll
            for (int r = 0; r < 4; ++r)
                S[kb][r] = exp2f(S[kb][r] - SFIX);
        #pragma unroll
        for (int r = 0; r < 4; ++r)
            lsum[r] += (S[0][r] + S[1][r]) + (S[2][r] + S[3][r]);

        // ---- P: C-layout -> per-wave LDS (swizzled) -> A-layout ----
        #pragma unroll
        for (int kb = 0; kb < 4; ++kb) {
            #pragma unroll
            for (int r = 0; r < 4; ++r) {
                const int prow = hi * 4 + r;
                const int pcol = kb * 16 + l15;
                const int byte = (prow * 128 + pcol * 2) ^ ((prow & 7) << 4);
                *reinterpret_cast<ushort*>(pw + byte) = f2bf(S[kb][r]);
            }
        }
        asm volatile("" ::: "memory");   // intra-wave LDS in-order
        const int pb0 = (l15 * 128 + hi * 16) ^ ((l15 & 7) << 4);
        const int pb1 = (l15 * 128 + hi * 16 + 64) ^ ((l15 & 7) << 4);
        bf16x8 pa0 = *reinterpret_cast<const bf16x8*>(pw + pb0);
        bf16x8 pa1 = *reinterpret_cast<const bf16x8*>(pw + pb1);
        // ---- PV from LDS V ----
        #pragma unroll
        for (int dt = 0; dt < 4; ++dt) {
            const int d = dt * 16 + l15;
            const int sw = (d & 7) << 4;
            bf16x8 v0 = *reinterpret_cast<const bf16x8*>(vc + ((d * 128 + hi * 16) ^ sw));
            bf16x8 v1 = *reinterpret_cast<const bf16x8*>(vc + ((d * 128 + hi * 16 + 64) ^ sw));
            O[dt] = __builtin_amdgcn_mfma_f32_16x16x32_bf16(pa0, v0, O[dt], 0, 0, 0);
            O[dt] = __builtin_amdgcn_mfma_f32_16x16x32_bf16(pa1, v1, O[dt], 0, 0, 0);
        }
        if (c + 8 < 33) { STAGE_WRITE(cur ^ 1) }
        __syncthreads();
        cur ^= 1;
    }

    DUMP(qtB)    // curB==1 always on exit
#undef STAGE_ISSUE
#undef STAGE_WRITE
#undef LOADQ
#undef DUMP
#undef RESET_STATE
}

// ---------------------------------------------------------------------------
// Kernel 3: out = Σ_s Opart[s] / Σ_s lpart[s].  bf16 partial reads, fp32
// accumulate, float4 x2 stores.  131072 threads.
// ---------------------------------------------------------------------------
__global__ __launch_bounds__(256) void merge_kernel(
    const ushort* __restrict__ Opart, const float* __restrict__ lpart,
    float* __restrict__ out)
{
    const int idx = blockIdx.x * 256 + threadIdx.x;    // 0..131071
    const int row = idx >> 3;
    float acc[8] = {0.f, 0.f, 0.f, 0.f, 0.f, 0.f, 0.f, 0.f};
    float lv = 0.f;
    #pragma unroll
    for (int s = 0; s < NSPLIT; ++s) {
        uint4 v = reinterpret_cast<const uint4*>(Opart + (size_t)s * NROWS * 64)[idx];
        const uint u0 = v.x, u1 = v.y, u2 = v.z, u3 = v.w;
        acc[0] += __uint_as_float((u0 & 0xffffu) << 16);
        acc[1] += __uint_as_float(u0 & 0xffff0000u);
        acc[2] += __uint_as_float((u1 & 0xffffu) << 16);
        acc[3] += __uint_as_float(u1 & 0xffff0000u);
        acc[4] += __uint_as_float((u2 & 0xffffu) << 16);
        acc[5] += __uint_as_float(u2 & 0xffff0000u);
        acc[6] += __uint_as_float((u3 & 0xffffu) << 16);
        acc[7] += __uint_as_float(u3 & 0xffff0000u);
        lv += lpart[s * NROWS + row];
    }
    const float inv = 1.0f / lv;
    float4 o0 = make_float4(acc[0] * inv, acc[1] * inv, acc[2] * inv, acc[3] * inv);
    float4 o1 = make_float4(acc[4] * inv, acc[5] * inv, acc[6] * inv, acc[7] * inv);
    reinterpret_cast<float4*>(out)[idx * 2]     = o0;
    reinterpret_cast<float4*>(out)[idx * 2 + 1] = o1;
}

extern "C" void kernel_launch(void* const* d_in, const int* in_sizes, int n_in,
                              void* d_out, int out_size, void* d_ws, size_t ws_size,
                              hipStream_t stream) {
    const float* x  = (const float*)d_in[0];
    const float* Wq = (const float*)d_in[1];
    const float* Wk = (const float*)d_in[2];
    const float* Wv = (const float*)d_in[3];
    float* out = (float*)d_out;

    ushort* qb   = (ushort*)d_ws;                    // 2MB
    ushort* kbuf = qb + (size_t)NROWS * 64;          // 2MB
    ushort* vt   = kbuf + (size_t)NROWS * 64;        // 2MB (transposed V)
    ushort* wp   = vt + (size_t)NROWS * 64;          // 384KB packed W^T
    float* lpart = (float*)(wp + 192 * 1024);        // 512KB  8 x row-sums
    ushort* Opart = (ushort*)(lpart + (size_t)NSPLIT * NROWS);  // 16MB  8 x bf16 O partials

    wpack_kernel<<<24, 256, 0, stream>>>(Wq, Wk, Wv, wp);
    qkv_gemm<<<NROWS / 32, 768, 0, stream>>>(x, wp, qb, kbuf, vt);
    attn_flash<<<1024, 256, 0, stream>>>(qb, kbuf, vt, Opart, lpart);
    merge_kernel<<<(NROWS * HDIM / 8) / 256, 256, 0, stream>>>(Opart, lpart, out);
}

// Round 22
// 50.300 us; speedup vs baseline: 1.0633x; 1.0075x over previous
//
#include <hip/hip_runtime.h>
#include <hip/hip_bf16.h>

#define BATCH 8
#define SEQ   2048
#define CDIM  1024
#define HDIM  64
#define NROWS (BATCH*SEQ)   // 16384
#define NSPLIT 8

typedef __attribute__((ext_vector_type(8))) short bf16x8;
typedef __attribute__((ext_vector_type(4))) float f32x4;

// 0.125 (1/sqrt(64)) * log2(e) — folded into Wq so QK^T emerges in exp2 units
#define QSCALE 0.18033688011112042f
// fixed softmax shift (exp2 units): scores bounded ~±8 << 24.  softmax is
// shift-invariant -> partials ADDITIVE (validated R6-R21: absmax 0.0156) ->
// cross-block merge = plain sums over per-split buffers.
#define SFIX 24.0f

__device__ inline ushort f2bf(float f) {
    union { float f; uint u; } x; x.f = f;
    uint r = (x.u + 0x7fffu + ((x.u >> 16) & 1u)) >> 16;
    return (ushort)r;
}

// ---------------------------------------------------------------------------
// Kernel 0: pack W^T into bf16  wp[192][1024] (R13 exact).
// ---------------------------------------------------------------------------
__global__ __launch_bounds__(256) void wpack_kernel(
    const float* __restrict__ Wq, const float* __restrict__ Wk,
    const float* __restrict__ Wv, ushort* __restrict__ wp)
{
    __shared__ ushort lt[64][132];
    const int which = blockIdx.x >> 3;         // 0..2
    const int cblk  = blockIdx.x & 7;          // 0..7
    const float* W = (which == 0) ? Wq : (which == 1) ? Wk : Wv;
    const float sc = (which == 0) ? QSCALE : 1.0f;
    const int t = threadIdx.x;
    const float4* Wb = reinterpret_cast<const float4*>(W + (size_t)cblk * 128 * 64);
    #pragma unroll
    for (int j = 0; j < 8; ++j) {
        const int off4 = j * 256 + t;          // 0..2047
        float4 v = Wb[off4];
        const int c = off4 >> 4;               // 0..127
        const int n0 = (off4 & 15) * 4;        // 0..60
        lt[n0 + 0][c] = f2bf(v.x * sc);
        lt[n0 + 1][c] = f2bf(v.y * sc);
        lt[n0 + 2][c] = f2bf(v.z * sc);
        lt[n0 + 3][c] = f2bf(v.w * sc);
    }
    __syncthreads();
    const int n = t >> 2, cq = (t & 3) * 32;
    ushort* dst = wp + (size_t)(which * 64 + n) * CDIM + cblk * 128 + cq;
    #pragma unroll
    for (int k = 0; k < 32; ++k) dst[k] = lt[n][cq + k];
}

// ---------------------------------------------------------------------------
// Kernel 1: QKV GEMM — R20 winner: 768-thread blocks (12 waves = 2 rowg x
// 6 colg, wave = 16 rows x 32 cols), BM=32 / 512 blocks / 56KB LDS ->
// 2 blocks/CU, 24 waves/CU.
// ---------------------------------------------------------------------------
__global__ __launch_bounds__(768, 2) void qkv_gemm(
    const float* __restrict__ x, const ushort* __restrict__ wp,
    ushort* __restrict__ qb, ushort* __restrict__ kbuf, ushort* __restrict__ vt)
{
    __shared__ ushort xs[2][32 * 64];    // 8KB   [row][c] bf16, XOR-swizzled
    __shared__ ushort ws[2][192 * 64];   // 48KB  [n][c]  bf16, XOR-swizzled
    const int t = threadIdx.x;
    const int w = t >> 6, lane = t & 63;
    const int l15 = lane & 15, hi = lane >> 4;
    const int rowg = w & 1, colg = w >> 1;     // colg 0..5
    const int m0 = blockIdx.x * 32;

    f32x4 acc[2];
    #pragma unroll
    for (int i = 0; i < 2; ++i) acc[i] = (f32x4){0.f, 0.f, 0.f, 0.f};

    const int xrow = t >> 4, xc4 = t & 15;
    const int wn0 = t >> 3,          wc0 = t & 7;
    const int wn1 = (t + 768) >> 3,  wc1 = (t + 768) & 7;

    float4 xra, xrb;
    uint4 wra0, wra1, wrb0, wrb1;

#define LOADS(S, KK)                                                           \
    if (t < 512)                                                               \
        xr##S = reinterpret_cast<const float4*>(x + (size_t)(m0 + xrow) * CDIM + (KK))[xc4]; \
    wr##S##0 = reinterpret_cast<const uint4*>(wp + (size_t)wn0 * CDIM + (KK))[wc0]; \
    wr##S##1 = reinterpret_cast<const uint4*>(wp + (size_t)wn1 * CDIM + (KK))[wc1];

#define WRITES(S, BUF)                                                         \
    {                                                                          \
        if (t < 512) {                                                         \
            ushort4 bx = make_ushort4(f2bf(xr##S.x), f2bf(xr##S.y), f2bf(xr##S.z), f2bf(xr##S.w)); \
            int xb = (xrow * 128 + xc4 * 8) ^ ((xrow & 7) << 4);               \
            *reinterpret_cast<ushort4*>(reinterpret_cast<char*>(xs[BUF]) + xb) = bx; \
        }                                                                      \
        int y0 = (wn0 * 128 + wc0 * 16) ^ ((wn0 & 7) << 4);                    \
        int y1 = (wn1 * 128 + wc1 * 16) ^ ((wn1 & 7) << 4);                    \
        *reinterpret_cast<uint4*>(reinterpret_cast<char*>(ws[BUF]) + y0) = wr##S##0; \
        *reinterpret_cast<uint4*>(reinterpret_cast<char*>(ws[BUF]) + y1) = wr##S##1; \
    }

#define MFMA_STEP(BUF)                                                         \
    {                                                                          \
        const int arow = rowg * 16 + l15;                                      \
        _Pragma("unroll")                                                      \
        for (int c32 = 0; c32 < 2; ++c32) {                                    \
            const int abyte = (arow * 128 + hi * 16 + c32 * 64) ^ ((arow & 7) << 4); \
            bf16x8 a = *reinterpret_cast<const bf16x8*>(reinterpret_cast<char*>(xs[BUF]) + abyte); \
            _Pragma("unroll")                                                  \
            for (int nf = 0; nf < 2; ++nf) {                                   \
                const int n = colg * 32 + nf * 16 + l15;                       \
                const int bbyte = (n * 128 + hi * 16 + c32 * 64) ^ ((n & 7) << 4); \
                bf16x8 b = *reinterpret_cast<const bf16x8*>(reinterpret_cast<char*>(ws[BUF]) + bbyte); \
                acc[nf] = __builtin_amdgcn_mfma_f32_16x16x32_bf16(a, b, acc[nf], 0, 0, 0); \
            }                                                                  \
        }                                                                      \
    }

    LOADS(a, 0)
    LOADS(b, 64)
    WRITES(a, 0)
    __syncthreads();

    for (int step = 0; step < 16; step += 2) {
        if (step + 2 < 16) { LOADS(a, (step + 2) * 64) }
        MFMA_STEP(0)
        WRITES(b, 1)
        __syncthreads();
        if (step + 3 < 16) { LOADS(b, (step + 3) * 64) }
        MFMA_STEP(1)
        if (step + 2 < 16) { WRITES(a, 0) }
        __syncthreads();
    }
#undef LOADS
#undef WRITES
#undef MFMA_STEP

    #pragma unroll
    for (int nf = 0; nf < 2; ++nf) {
        const int n = colg * 32 + nf * 16 + l15;
        #pragma unroll
        for (int r = 0; r < 4; ++r) {
            const int grow = m0 + rowg * 16 + hi * 4 + r;
            const ushort bv = f2bf(acc[nf][r]);
            if (n < 64) {
                qb[(size_t)grow * 64 + n] = bv;
            } else if (n < 128) {
                kbuf[(size_t)grow * 64 + (n - 64)] = bv;
            } else {
                const int b = grow >> 11, tt = grow & 2047;
                vt[(((size_t)b * 64 + (n - 128)) << 11) + tt] = bv;
            }
        }
    }
}

// ---------------------------------------------------------------------------
// Kernel 2: flash attention — R13 loop with SINGLE-BUFFERED K/V LDS.
// R21 audit: the double-buffered version's 41,472B LDS fit only 3 blocks/CU
// (12 waves/CU) — an occupancy cliff.  Single-buffer (24KB+P=25KB -> 6
// blocks/CU capacity, grid-limited 4/CU = 16 waves/CU).  Prefetch latency is
// still hidden in the REGISTER stage (STAGE_ISSUE one tile ahead); the LDS
// buffer only ever holds the current tile.  Cost: 2nd barrier per tile.
// ---------------------------------------------------------------------------
__global__ __launch_bounds__(256, 4) void attn_flash(
    const ushort* __restrict__ qb, const ushort* __restrict__ kbuf,
    const ushort* __restrict__ vt, ushort* __restrict__ Opart,
    float* __restrict__ lpart)
{
    __shared__ ushort kst[64 * 64];      // 8KB  K tile, XOR-swizzled (single)
    __shared__ ushort vst[64 * 64];      // 8KB  V tile (vt layout [d][t])
    __shared__ ushort P[4][1024];        // 8KB  per-wave P round-trip

    const int t = threadIdx.x;
    const int w = t >> 6, lane = t & 63;
    const int l15 = lane & 15, hi = lane >> 4;
    const int bid = blockIdx.x;
    const int pid = (bid & 7) * 128 + (bid >> 3);   // XCD x -> batch x
    const int batch = pid >> 7;
    const int rem = pid & 127;
    const int pairIdx = rem >> 3;        // 0..15
    const int s = rem & 7;               // split 0..7
    const int qtA = pairIdx, qtB = 31 - pairIdx;    // 64-row q-tiles
    const int ntA = qtA + 1;             // ntA + ntB == 33

    const ushort* kB = kbuf + (size_t)batch * SEQ * 64;
    const ushort* vB = vt + (size_t)batch * 64 * SEQ;
    ushort* Osp = Opart + (size_t)s * NROWS * 64;
    float* lsp = lpart + (size_t)s * NROWS;
    char* pw = reinterpret_cast<char*>(P[w]);

    const int r0 = t >> 3, c8 = t & 7;   // chunk0 row 0..31
    const int r1 = r0 + 32;              // chunk1 row 32..63
    const int sb0 = (r0 * 128 + c8 * 16) ^ ((r0 & 7) << 4);
    const int sb1 = (r1 * 128 + c8 * 16) ^ ((r1 & 7) << 4);

    uint4 kr0, kr1, vr0, vr1;

#define STAGE_ISSUE(C)                                                        \
    {                                                                         \
        const int kt_ = ((C) >= ntA) ? ((C) - ntA) : (C);                     \
        const int j0_ = kt_ * 64;                                             \
        kr0 = *reinterpret_cast<const uint4*>(kB + (size_t)(j0_ + r0) * 64 + c8 * 8); \
        kr1 = *reinterpret_cast<const uint4*>(kB + (size_t)(j0_ + r1) * 64 + c8 * 8); \
        vr0 = *reinterpret_cast<const uint4*>(vB + (size_t)r0 * SEQ + j0_ + c8 * 8);  \
        vr1 = *reinterpret_cast<const uint4*>(vB + (size_t)r1 * SEQ + j0_ + c8 * 8);  \
    }

#define STAGE_WRITE()                                                         \
    {                                                                         \
        *reinterpret_cast<uint4*>(reinterpret_cast<char*>(kst) + sb0) = kr0;  \
        *reinterpret_cast<uint4*>(reinterpret_cast<char*>(kst) + sb1) = kr1;  \
        *reinterpret_cast<uint4*>(reinterpret_cast<char*>(vst) + sb0) = vr0;  \
        *reinterpret_cast<uint4*>(reinterpret_cast<char*>(vst) + sb1) = vr1;  \
    }

#define LOADQ(QT)                                                             \
    {                                                                         \
        const ushort* qp_ = qb + (size_t)(batch * SEQ + (QT) * 64 + w * 16 + l15) * 64 + hi * 8; \
        aq0 = *reinterpret_cast<const bf16x8*>(qp_);                          \
        aq1 = *reinterpret_cast<const bf16x8*>(qp_ + 32);                     \
    }

#define DUMP(QT)                                                              \
    {                                                                         \
        _Pragma("unroll")                                                     \
        for (int dt = 0; dt < 4; ++dt)                                        \
            _Pragma("unroll")                                                 \
            for (int r = 0; r < 4; ++r)                                       \
                Osp[(size_t)(batch * SEQ + (QT) * 64 + w * 16 + hi * 4 + r) * 64 + dt * 16 + l15] = f2bf(O[dt][r]); \
        _Pragma("unroll")                                                     \
        for (int r = 0; r < 4; ++r) {                                         \
            float s_ = lsum[r];                                               \
            s_ += __shfl_xor(s_, 1, 64);                                      \
            s_ += __shfl_xor(s_, 2, 64);                                      \
            s_ += __shfl_xor(s_, 4, 64);                                      \
            s_ += __shfl_xor(s_, 8, 64);                                      \
            if (l15 == 0)                                                     \
                lsp[batch * SEQ + (QT) * 64 + w * 16 + hi * 4 + r] = s_;      \
        }                                                                     \
    }

#define RESET_STATE()                                                         \
    {                                                                         \
        _Pragma("unroll")                                                     \
        for (int i = 0; i < 4; ++i) {                                         \
            O[i] = (f32x4){0.f, 0.f, 0.f, 0.f};                               \
            lsum[i] = 0.f;                                                    \
        }                                                                     \
    }

    bf16x8 aq0, aq1;
    LOADQ(qtA)
    f32x4 O[4];
    float lsum[4];
    RESET_STATE()

    STAGE_ISSUE(s)
    STAGE_WRITE()
    __syncthreads();

    int curB = 0;
    for (int c = s; c < 33; c += 8) {
        if (c + 8 < 33) { STAGE_ISSUE(c + 8) }    // regs, in flight over compute
        if (c >= ntA && !curB) {                  // block-uniform A -> B
            DUMP(qtA)
            RESET_STATE()
            LOADQ(qtB)
            curB = 1;
        }
        const int qt = curB ? qtB : qtA;
        const int kt = curB ? (c - ntA) : c;
        const int j0 = kt * 64;
        const int qrow0 = qt * 64 + w * 16;
        const bool diag = curB ? (c == 32) : (c == ntA - 1);

        const char* kc = reinterpret_cast<const char*>(kst);
        const char* vc = reinterpret_cast<const char*>(vst);

        // ---- QK^T from LDS K ----
        f32x4 S[4];
        #pragma unroll
        for (int kb = 0; kb < 4; ++kb) {
            const int key = kb * 16 + l15;
            const int sw = (key & 7) << 4;
            bf16x8 b0 = *reinterpret_cast<const bf16x8*>(kc + ((key * 128 + hi * 16) ^ sw));
            bf16x8 b1 = *reinterpret_cast<const bf16x8*>(kc + ((key * 128 + hi * 16 + 64) ^ sw));
            f32x4 z = (f32x4){0.f, 0.f, 0.f, 0.f};
            z = __builtin_amdgcn_mfma_f32_16x16x32_bf16(aq0, b0, z, 0, 0, 0);
            z = __builtin_amdgcn_mfma_f32_16x16x32_bf16(aq1, b1, z, 0, 0, 0);
            S[kb] = z;
        }
        // ---- causal mask: only the diagonal tile ----
        if (diag) {
            #pragma unroll
            for (int kb = 0; kb < 4; ++kb) {
                const int key = j0 + kb * 16 + l15;
                #pragma unroll
                for (int r = 0; r < 4; ++r) {
                    const int qr = qrow0 + hi * 4 + r;
                    if (key > qr) S[kb][r] = -1e30f;
                }
            }
        }
        // ---- fixed-shift softmax ----
        #pragma unroll
        for (int kb = 0; kb < 4; ++kb)
            #pragma unroll
            for (int r = 0; r < 4; ++r)
                S[kb][r] = exp2f(S[kb][r] - SFIX);
        #pragma unroll
        for (int r = 0; r < 4; ++r)
            lsum[r] += (S[0][r] + S[1][r]) + (S[2][r] + S[3][r]);

        // ---- P: C-layout -> per-wave LDS (swizzled) -> A-layout ----
        #pragma unroll
        for (int kb = 0; kb < 4; ++kb) {
            #pragma unroll
            for (int r = 0; r < 4; ++r) {
                const int prow = hi * 4 + r;
                const int pcol = kb * 16 + l15;
                const int byte = (prow * 128 + pcol * 2) ^ ((prow & 7) << 4);
                *reinterpret_cast<ushort*>(pw + byte) = f2bf(S[kb][r]);
            }
        }
        asm volatile("" ::: "memory");   // intra-wave LDS in-order
        const int pb0 = (l15 * 128 + hi * 16) ^ ((l15 & 7) << 4);
        const int pb1 = (l15 * 128 + hi * 16 + 64) ^ ((l15 & 7) << 4);
        bf16x8 pa0 = *reinterpret_cast<const bf16x8*>(pw + pb0);
        bf16x8 pa1 = *reinterpret_cast<const bf16x8*>(pw + pb1);
        // ---- PV from LDS V ----
        #pragma unroll
        for (int dt = 0; dt < 4; ++dt) {
            const int d = dt * 16 + l15;
            const int sw = (d & 7) << 4;
            bf16x8 v0 = *reinterpret_cast<const bf16x8*>(vc + ((d * 128 + hi * 16) ^ sw));
            bf16x8 v1 = *reinterpret_cast<const bf16x8*>(vc + ((d * 128 + hi * 16 + 64) ^ sw));
            O[dt] = __builtin_amdgcn_mfma_f32_16x16x32_bf16(pa0, v0, O[dt], 0, 0, 0);
            O[dt] = __builtin_amdgcn_mfma_f32_16x16x32_bf16(pa1, v1, O[dt], 0, 0, 0);
        }
        // ---- single buffer: all done reading, then overwrite, then visible ----
        __syncthreads();
        if (c + 8 < 33) {
            STAGE_WRITE()
            __syncthreads();
        }
    }

    DUMP(qtB)    // curB==1 always on exit
#undef STAGE_ISSUE
#undef STAGE_WRITE
#undef LOADQ
#undef DUMP
#undef RESET_STATE
}

// ---------------------------------------------------------------------------
// Kernel 3: out = Σ_s Opart[s] / Σ_s lpart[s].  bf16 partial reads, fp32
// accumulate, float4 x2 stores.  131072 threads.
// ---------------------------------------------------------------------------
__global__ __launch_bounds__(256) void merge_kernel(
    const ushort* __restrict__ Opart, const float* __restrict__ lpart,
    float* __restrict__ out)
{
    const int idx = blockIdx.x * 256 + threadIdx.x;    // 0..131071
    const int row = idx >> 3;
    float acc[8] = {0.f, 0.f, 0.f, 0.f, 0.f, 0.f, 0.f, 0.f};
    float lv = 0.f;
    #pragma unroll
    for (int s = 0; s < NSPLIT; ++s) {
        uint4 v = reinterpret_cast<const uint4*>(Opart + (size_t)s * NROWS * 64)[idx];
        const uint u0 = v.x, u1 = v.y, u2 = v.z, u3 = v.w;
        acc[0] += __uint_as_float((u0 & 0xffffu) << 16);
        acc[1] += __uint_as_float(u0 & 0xffff0000u);
        acc[2] += __uint_as_float((u1 & 0xffffu) << 16);
        acc[3] += __uint_as_float(u1 & 0xffff0000u);
        acc[4] += __uint_as_float((u2 & 0xffffu) << 16);
        acc[5] += __uint_as_float(u2 & 0xffff0000u);
        acc[6] += __uint_as_float((u3 & 0xffffu) << 16);
        acc[7] += __uint_as_float(u3 & 0xffff0000u);
        lv += lpart[s * NROWS + row];
    }
    const float inv = 1.0f / lv;
    float4 o0 = make_float4(acc[0] * inv, acc[1] * inv, acc[2] * inv, acc[3] * inv);
    float4 o1 = make_float4(acc[4] * inv, acc[5] * inv, acc[6] * inv, acc[7] * inv);
    reinterpret_cast<float4*>(out)[idx * 2]     = o0;
    reinterpret_cast<float4*>(out)[idx * 2 + 1] = o1;
}

extern "C" void kernel_launch(void* const* d_in, const int* in_sizes, int n_in,
                              void* d_out, int out_size, void* d_ws, size_t ws_size,
                              hipStream_t stream) {
    const float* x  = (const float*)d_in[0];
    const float* Wq = (const float*)d_in[1];
    const float* Wk = (const float*)d_in[2];
    const float* Wv = (const float*)d_in[3];
    float* out = (float*)d_out;

    ushort* qb   = (ushort*)d_ws;                    // 2MB
    ushort* kbuf = qb + (size_t)NROWS * 64;          // 2MB
    ushort* vt   = kbuf + (size_t)NROWS * 64;        // 2MB (transposed V)
    ushort* wp   = vt + (size_t)NROWS * 64;          // 384KB packed W^T
    float* lpart = (float*)(wp + 192 * 1024);        // 512KB  8 x row-sums
    ushort* Opart = (ushort*)(lpart + (size_t)NSPLIT * NROWS);  // 16MB  8 x bf16 O partials

    wpack_kernel<<<24, 256, 0, stream>>>(Wq, Wk, Wv, wp);
    qkv_gemm<<<NROWS / 32, 768, 0, stream>>>(x, wp, qb, kbuf, vt);
    attn_flash<<<1024, 256, 0, stream>>>(qb, kbuf, vt, Opart, lpart);
    merge_kernel<<<(NROWS * HDIM / 8) / 256, 256, 0, stream>>>(Opart, lpart, out);
}